// Round 9
// baseline (67.647 us; speedup 1.0000x reference)
//
#include <hip/hip_runtime.h>
#include <math.h>

#define NT  192          // 3 waves; wave id == anchor
#define PXW 64           // pixels per span, wide (26/52) levels: 2 px/thread
#define PXS 32           // pixels per block, 13 level: 1 px/thread
#define FR  48           // rows per flush phase; LDS = 48*90*4 = 17280 B -> 9 blocks/CU

typedef float vf4 __attribute__((ext_vector_type(4)));
typedef float vf2 __attribute__((ext_vector_type(2)));

__device__ __forceinline__ float sigf(float x) { return 1.0f / (1.0f + expf(-x)); }

__device__ __forceinline__ void flush4(const float* __restrict__ lds,
                                       float* __restrict__ outp, int nfl, int tid)
{
    vf4* d4 = (vf4*)outp;
    const vf4* s4 = (const vf4*)lds;
    for (int i = tid; i < (nfl >> 2); i += NT) d4[i] = s4[i];
}
__device__ __forceinline__ void flush2(const float* __restrict__ lds,
                                       float* __restrict__ outp, int nfl, int tid)
{
    vf2* d2 = (vf2*)outp;
    const vf2* s2 = (const vf2*)lds;
    for (int i = tid; i < (nfl >> 1); i += NT) d2[i] = s2[i];
}

// Wide levels: wave a, lane = (h, p2): pixels q0=2*p2,q0+1, entries [45h,45h+45).
// Grid-stride 2 spans per block; the next span's first 5 channels (the scalar
// inputs for h==0) are prefetched before the current span's flush, so the
// load->s->transform critical path of span k+1 overlaps span k's flush.
template<int H, int W, int T>
__device__ __forceinline__ void decode_wide(
    const float* __restrict__ in, const float* __restrict__ anchors,
    float th, float invCase, float* __restrict__ out, long gRowBase,
    int blk0, int halfSpan, float* __restrict__ lds)
{
    constexpr int HW = H * W;
    constexpr int SPANS = (HW + PXW - 1) / PXW;
    const int tid = threadIdx.x;
    const int a = tid >> 6, lane = tid & 63, h = lane >> 5, p2 = lane & 31;
    const int q0 = 2 * p2;

    float n0[5] = {0, 0, 0, 0, 0}, n1[5] = {0, 0, 0, 0, 0};
    {   // prefetch first-5 for iteration 0
        const int b = blk0 / SPANS, P0 = (blk0 % SPANS) * PXW;
        const int npix = (HW - P0 < PXW) ? (HW - P0) : PXW;
        if (q0 < npix) {
            const float* src = in + ((long)b * 270 + a * 90 + 45 * h) * HW + P0 + q0;
            #pragma unroll
            for (int j = 0; j < 5; ++j) {
                vf2 t2 = *(const vf2*)(src + (long)j * HW);
                n0[j] = t2.x; n1[j] = t2.y;
            }
        }
    }

    for (int it = 0; it < 2; ++it) {
        const int blkL = blk0 + it * halfSpan;
        const int b = blkL / SPANS, P0 = (blkL % SPANS) * PXW;
        const int npix = (HW - P0 < PXW) ? (HW - P0) : PXW;   // even tails
        const bool act = q0 < npix;
        const float* src = in + ((long)b * 270 + a * 90 + 45 * h) * HW + P0 + q0;

        float v0[45], v1[45];
        #pragma unroll
        for (int j = 0; j < 5; ++j) { v0[j] = n0[j]; v1[j] = n1[j]; }
        if (act) {
            #pragma unroll
            for (int j = 5; j < 45; ++j) {
                vf2 t2 = *(const vf2*)(src + (long)j * HW);
                v0[j] = t2.x; v1[j] = t2.y;
            }
        }

        // Row scalars valid on h==0 lanes (their v[0..4] = channels 0..4).
        float sp0 = sigf(v0[0]), sp1 = sigf(v1[0]);
        bool  m0 = sp0 > th,     m1 = sp1 > th;
        float A0 = anchors[a * 2 + 0], A1 = anchors[a * 2 + 1];
        float w0 = A0 * expf(v0[3]), w1 = A0 * expf(v1[3]);
        float h0 = A1 * expf(v0[4]), h1 = A1 * expf(v1[4]);
        float s0 = sqrtf(w0 * w0 + h0 * h0) * invCase;
        float s1 = sqrtf(w1 * w1 + h1 * h1) * invCase;
        int pix0 = P0 + q0;
        int x0 = pix0 % W, y0 = pix0 / W;
        int x1 = (pix0 + 1) % W, y1 = (pix0 + 1) / W;
        float cx0 = ((float)x0 + v0[1]) * (float)T, cy0 = ((float)y0 + v0[2]) * (float)T;
        float cx1 = ((float)x1 + v1[1]) * (float)T, cy1 = ((float)y1 + v1[2]) * (float)T;

        float ms0 = __shfl(m0 ? s0 : 0.0f, p2, 64);   // h0 -> h1 broadcast
        float ms1 = __shfl(m1 ? s1 : 0.0f, p2, 64);
        float mf0 = __shfl(m0 ? 1.0f : 0.0f, p2, 64);
        float mf1 = __shfl(m1 ? 1.0f : 0.0f, p2, 64);
        const bool mB0 = mf0 > 0.5f, mB1 = mf1 > 0.5f;

        #pragma unroll
        for (int j = 0; j < 45; ++j) {
            // k = 45h+j; coord iff j%3==0; point region k in [6,18) is h==0-only.
            bool coord = (j % 3 == 0), pt = (j >= 6 && j < 18);
            float a0 = v0[j], a1 = v1[j];
            if (coord)   { v0[j] = a0 * ms0;  v1[j] = a1 * ms1; }
            else if (pt) { v0[j] = (h == 0) ? a0 * ms0 : (mB0 ? sigf(a0) : 0.0f);
                           v1[j] = (h == 0) ? a1 * ms1 : (mB1 ? sigf(a1) : 0.0f); }
            else         { v0[j] = mB0 ? sigf(a0) : 0.0f;
                           v1[j] = mB1 ? sigf(a1) : 0.0f; }
        }
        if (h == 0) {   // obj entries 0..5 (local m/s valid on h==0)
            v0[0] = m0 ? (float)b : 0.0f;  v1[0] = m1 ? (float)b : 0.0f;
            v0[1] = m0 ? sp0 : 0.0f;       v1[1] = m1 ? sp1 : 0.0f;
            v0[2] = m0 ? cx0 : 0.0f;       v1[2] = m1 ? cx1 : 0.0f;
            v0[3] = m0 ? cy0 : 0.0f;       v1[3] = m1 ? cy1 : 0.0f;
            v0[4] = m0 ? w0  : 0.0f;       v1[4] = m1 ? w1  : 0.0f;
            v0[5] = m0 ? h0  : 0.0f;       v1[5] = m1 ? h1  : 0.0f;
        }

        // Prefetch iteration 1's first-5 while this span flushes.
        if (it == 0) {
            const int blkN = blk0 + halfSpan;
            const int bN = blkN / SPANS, P0N = (blkN % SPANS) * PXW;
            const int npixN = (HW - P0N < PXW) ? (HW - P0N) : PXW;
            if (q0 < npixN) {
                const float* srcN = in + ((long)bN * 270 + a * 90 + 45 * h) * HW + P0N + q0;
                #pragma unroll
                for (int j = 0; j < 5; ++j) {
                    vf2 t2 = *(const vf2*)(srcN + (long)j * HW);
                    n0[j] = t2.x; n1[j] = t2.y;
                }
            }
        }

        const size_t gbase = (size_t)(gRowBase + ((long)b * HW + P0) * 3) * 90;
        const int myf = p2 >> 3;       // both pixels of a thread share a phase

        #pragma unroll
        for (int f = 0; f < PXW / 16; ++f) {
            int pf = npix - 16 * f;
            if (pf <= 0) break;        // block-uniform
            if (pf > 16) pf = 16;
            if (act && myf == f) {
                float* dst = lds + ((q0 - 16 * f) * 3 + a) * 90 + 45 * h;
                #pragma unroll
                for (int j = 0; j < 45; ++j) dst[j] = v0[j];
                dst += 270;
                #pragma unroll
                for (int j = 0; j < 45; ++j) dst[j] = v1[j];
            }
            __syncthreads();
            flush4(lds, out + gbase + (size_t)f * FR * 90, pf * 3 * 90, tid);
            __syncthreads();
        }
    }
}

// 13-level (HW=169, odd): scalar path, two-phase staging, float2 flush.
__device__ __forceinline__ void decode13(
    const float* __restrict__ in, const float* __restrict__ anchors,
    float th, float invCase, float* __restrict__ out,
    int blkL, float* __restrict__ lds)
{
    constexpr int H = 13, W = 13, T = 32, HW = 169;
    constexpr int SPANS = (HW + PXS - 1) / PXS;     // 6
    const int b    = blkL / SPANS;
    const int P0   = (blkL % SPANS) * PXS;
    const int npix = (HW - P0 < PXS) ? (HW - P0) : PXS;

    const int tid = threadIdx.x;
    const int a = tid >> 6, lane = tid & 63, h = lane >> 5, p = lane & 31;
    const bool act = p < npix;

    float v[45];
    if (act) {
        const int pix = P0 + p;
        const int x = pix % W, y = pix / W;
        const float* src = in + ((long)b * 270 + a * 90 + 45 * h) * HW + pix;
        #pragma unroll
        for (int j = 0; j < 45; ++j) v[j] = src[(long)j * HW];

        float sp = sigf(v[0]);
        bool  m  = sp > th;
        float A0 = anchors[a * 2 + 0], A1 = anchors[a * 2 + 1];
        float w  = A0 * expf(v[3]);
        float hb = A1 * expf(v[4]);
        float s  = sqrtf(w * w + hb * hb) * invCase;
        float cx = ((float)x + v[1]) * (float)T;
        float cy = ((float)y + v[2]) * (float)T;

        float ms = __shfl(m ? s : 0.0f, p, 64);
        float mf = __shfl(m ? 1.0f : 0.0f, p, 64);
        const bool mB = mf > 0.5f;

        #pragma unroll
        for (int j = 0; j < 45; ++j) {
            float val = v[j];
            bool coord = (j % 3 == 0), pt = (j >= 6 && j < 18);
            if (coord)   v[j] = val * ms;
            else if (pt) v[j] = (h == 0) ? val * ms : (mB ? sigf(val) : 0.0f);
            else         v[j] = mB ? sigf(val) : 0.0f;
        }
        if (h == 0) {
            v[0] = m ? (float)b : 0.0f;
            v[1] = m ? sp       : 0.0f;
            v[2] = m ? cx       : 0.0f;
            v[3] = m ? cy       : 0.0f;
            v[4] = m ? w        : 0.0f;
            v[5] = m ? hb       : 0.0f;
        }
    }

    const size_t gbase = (size_t)(((long)b * HW + P0) * 3) * 90;

    if (act && p < 16) {
        float* dst = lds + (p * 3 + a) * 90 + 45 * h;
        #pragma unroll
        for (int j = 0; j < 45; ++j) dst[j] = v[j];
    }
    __syncthreads();
    int nA = npix < 16 ? npix : 16;
    flush2(lds, out + gbase, nA * 3 * 90, tid);

    int nB = npix - 16;
    if (nB > 0) {
        __syncthreads();
        if (act && p >= 16) {
            float* dst = lds + ((p - 16) * 3 + a) * 90 + 45 * h;
            #pragma unroll
            for (int j = 0; j < 45; ++j) dst[j] = v[j];
        }
        __syncthreads();
        flush2(lds, out + gbase + (size_t)FR * 90, nB * 3 * 90, tid);
    }
}

__global__ __launch_bounds__(NT, 4) void decode_all(
    const float* __restrict__ in13, const float* __restrict__ in26,
    const float* __restrict__ in52,
    const float* __restrict__ anc13, const float* __restrict__ anc26,
    const float* __restrict__ anc52,
    const float* __restrict__ thresh, const int* __restrict__ casep,
    float* __restrict__ out, int nb52h, int nb26h, long rows13, long rows26)
{
    __shared__ float lds[FR * 90];
    const float th = thresh[0];
    const float invCase = 1.0f / (float)(*casep);
    const int blk = blockIdx.x;

    if (blk < nb52h)
        decode_wide<52, 52, 8>(in52, anc52, th, invCase, out,
                               rows13 + rows26, blk, nb52h, lds);
    else if (blk < nb52h + nb26h)
        decode_wide<26, 26, 16>(in26, anc26, th, invCase, out,
                                rows13, blk - nb52h, nb26h, lds);
    else
        decode13(in13, anc13, th, invCase, out, blk - nb52h - nb26h, lds);
}

extern "C" void kernel_launch(void* const* d_in, const int* in_sizes, int n_in,
                              void* d_out, int out_size, void* d_ws, size_t ws_size,
                              hipStream_t stream) {
    const float* in13  = (const float*)d_in[0];
    const float* in26  = (const float*)d_in[1];
    const float* in52  = (const float*)d_in[2];
    const float* anc13 = (const float*)d_in[3];
    const float* anc26 = (const float*)d_in[4];
    const float* anc52 = (const float*)d_in[5];
    const float* th    = (const float*)d_in[6];
    const int*   casep = (const int*)d_in[7];
    float* out = (float*)d_out;

    int B = in_sizes[0] / (270 * 13 * 13);   // 32

    long rows13 = (long)B * 13 * 13 * 3;
    long rows26 = (long)B * 26 * 26 * 3;

    int nblk13 = B * ((13 * 13 + PXS - 1) / PXS);       // 32*6  = 192
    int nb26h  = B * ((26 * 26 + PXW - 1) / PXW) / 2;   // 352/2 = 176
    int nb52h  = B * ((52 * 52 + PXW - 1) / PXW) / 2;   // 1376/2 = 688

    decode_all<<<dim3(nb52h + nb26h + nblk13), dim3(NT), 0, stream>>>(
        in13, in26, in52, anc13, anc26, anc52, th, casep, out,
        nb52h, nb26h, rows13, rows26);
}

// Round 10
// 53.093 us; speedup vs baseline: 1.2741x; 1.2741x over previous
//
#include <hip/hip_runtime.h>
#include <math.h>

#define PX 32            // pixels per block (shared across 3 anchor-waves)
#define NT 192           // 3 waves: wave id == anchor
#define HPX 16           // pixels staged per flush phase
#define LROWS (HPX * 3)  // 48 rows in LDS -> 17280 B -> 9 blocks/CU

// Precise sigmoid: used ONLY for the mask decision sigmoid(p) > thresh.
__device__ __forceinline__ float sigf(float x) { return 1.0f / (1.0f + expf(-x)); }
// Fast value-path math: v_exp_f32 / v_rcp_f32 (rel err ~1e-6, vs 322 absmax budget).
__device__ __forceinline__ float fexp(float x) { return __expf(x); }
__device__ __forceinline__ float fsig(float x) {
    return __builtin_amdgcn_rcpf(1.0f + __expf(-x));
}

template<bool F4>
__device__ __forceinline__ void flushLds(const float* __restrict__ lds,
                                         float* __restrict__ outp, int nfl, int tid)
{
    if (F4) {
        float4* d4 = (float4*)outp;
        const float4* s4 = (const float4*)lds;
        for (int i = tid; i < (nfl >> 2); i += NT) d4[i] = s4[i];
        int rem = nfl & 3, tail = nfl & ~3;
        if (tid < rem) outp[tail + tid] = lds[tail + tid];
    } else {
        float2* d2 = (float2*)outp;
        const float2* s2 = (const float2*)lds;
        for (int i = tid; i < (nfl >> 1); i += NT) d2[i] = s2[i];
    }
}

// Wave a, lane = (h = lane>>5, p = lane&31): row (pixel P0+p, anchor a), entries
// k in [45h, 45h+45). Per j the wave reads two 128B pixel-clusters (full lines).
// Two-phase LDS staging: pixels [0,16) then [16,32) through a [48][90] buffer.
template<int H, int W, int T, bool F4>
__device__ __forceinline__ void decode_level(
    const float* __restrict__ in, const float* __restrict__ anchors,
    float th, float invCase, float* __restrict__ out, long gRowBase,
    int blkL, float* __restrict__ lds)
{
    constexpr int HW = H * W;
    constexpr int SPANS = (HW + PX - 1) / PX;
    const int b    = blkL / SPANS;
    const int P0   = (blkL % SPANS) * PX;
    const int npix = (HW - P0 < PX) ? (HW - P0) : PX;

    const int tid  = threadIdx.x;
    const int a    = tid >> 6;
    const int lane = tid & 63;
    const int h    = lane >> 5;
    const int p    = lane & 31;
    const bool act = (p < npix);

    float v[45];
    if (act) {
        const int pix = P0 + p;
        const int x   = pix % W;
        const int y   = pix / W;
        const float* src = in + ((long)b * 270 + a * 90 + 45 * h) * HW + pix;

        #pragma unroll
        for (int j = 0; j < 45; ++j) v[j] = src[(long)j * HW];

        // Per-row scalars: valid on h==0 lanes (their v[0..4] are channels 0..4).
        float sp = sigf(v[0]);              // PRECISE: decides the mask
        bool  m  = sp > th;
        float A0 = anchors[a * 2 + 0], A1 = anchors[a * 2 + 1];
        float w  = A0 * fexp(v[3]);
        float hb = A1 * fexp(v[4]);
        float s  = sqrtf(w * w + hb * hb) * invCase;
        float cx = ((float)x + v[1]) * (float)T;
        float cy = ((float)y + v[2]) * (float)T;

        float ms = __shfl(m ? s : 0.0f, p, 64);       // broadcast h0 -> h1 partner
        float mf = __shfl(m ? 1.0f : 0.0f, p, 64);
        const bool mB = mf > 0.5f;

        #pragma unroll
        for (int j = 0; j < 45; ++j) {
            float val = v[j];
            // k = 45h+j; coord iff k%3==0 (== j%3==0); point region k in [6,18)
            // exists only on h==0 and is all coords scaled by s.
            bool coordAlways = (j % 3 == 0);
            bool pointRegion = (j >= 6 && j < 18);
            if (coordAlways)      v[j] = val * ms;
            else if (pointRegion) v[j] = (h == 0) ? val * ms : (mB ? fsig(val) : 0.0f);
            else                  v[j] = mB ? fsig(val) : 0.0f;
        }
        if (h == 0) {   // obj entries 0..5 override (local m/s valid on h==0)
            v[0] = m ? (float)b : 0.0f;
            v[1] = m ? sp       : 0.0f;
            v[2] = m ? cx       : 0.0f;
            v[3] = m ? cy       : 0.0f;
            v[4] = m ? w        : 0.0f;
            v[5] = m ? hb       : 0.0f;
        }
    }

    const size_t gbase = (size_t)(gRowBase + ((long)b * HW + P0) * 3) * 90;

    // ---- phase A: pixels [0, HPX) ----
    if (act && p < HPX) {
        float* dst = lds + (p * 3 + a) * 90 + 45 * h;
        #pragma unroll
        for (int j = 0; j < 45; ++j) dst[j] = v[j];
    }
    __syncthreads();
    int npixA = npix < HPX ? npix : HPX;
    flushLds<F4>(lds, out + gbase, npixA * 3 * 90, tid);

    // ---- phase B: pixels [HPX, PX) ----
    int npixB = npix - HPX;
    if (npixB > 0) {
        __syncthreads();
        if (act && p >= HPX) {
            float* dst = lds + ((p - HPX) * 3 + a) * 90 + 45 * h;
            #pragma unroll
            for (int j = 0; j < 45; ++j) dst[j] = v[j];
        }
        __syncthreads();
        flushLds<F4>(lds, out + gbase + (size_t)LROWS * 90, npixB * 3 * 90, tid);
    }
}

__global__ __launch_bounds__(NT, 6) void decode_all(
    const float* __restrict__ in13, const float* __restrict__ in26,
    const float* __restrict__ in52,
    const float* __restrict__ anc13, const float* __restrict__ anc26,
    const float* __restrict__ anc52,
    const float* __restrict__ thresh, const int* __restrict__ casep,
    float* __restrict__ out, int nblk52, int nblk26, long rows13, long rows26)
{
    __shared__ float lds[LROWS * 90];
    const float th = thresh[0];
    const float invCase = 1.0f / (float)(*casep);
    const int blk = blockIdx.x;

    if (blk < nblk52)
        decode_level<52, 52, 8, true>(in52, anc52, th, invCase, out,
                                      rows13 + rows26, blk, lds);
    else if (blk < nblk52 + nblk26)
        decode_level<26, 26, 16, true>(in26, anc26, th, invCase, out,
                                       rows13, blk - nblk52, lds);
    else
        decode_level<13, 13, 32, false>(in13, anc13, th, invCase, out,
                                        0, blk - nblk52 - nblk26, lds);
}

extern "C" void kernel_launch(void* const* d_in, const int* in_sizes, int n_in,
                              void* d_out, int out_size, void* d_ws, size_t ws_size,
                              hipStream_t stream) {
    const float* in13  = (const float*)d_in[0];
    const float* in26  = (const float*)d_in[1];
    const float* in52  = (const float*)d_in[2];
    const float* anc13 = (const float*)d_in[3];
    const float* anc26 = (const float*)d_in[4];
    const float* anc52 = (const float*)d_in[5];
    const float* th    = (const float*)d_in[6];
    const int*   casep = (const int*)d_in[7];
    float* out = (float*)d_out;

    int B = in_sizes[0] / (270 * 13 * 13);   // 32

    long rows13 = (long)B * 13 * 13 * 3;
    long rows26 = (long)B * 26 * 26 * 3;

    int nblk13 = B * ((13 * 13 + PX - 1) / PX);    // 32*6   = 192
    int nblk26 = B * ((26 * 26 + PX - 1) / PX);    // 32*22  = 704
    int nblk52 = B * ((52 * 52 + PX - 1) / PX);    // 32*85  = 2720

    decode_all<<<dim3(nblk52 + nblk26 + nblk13), dim3(NT), 0, stream>>>(
        in13, in26, in52, anc13, anc26, anc52, th, casep, out,
        nblk52, nblk26, rows13, rows26);
}